// Round 2
// baseline (947.794 us; speedup 1.0000x reference)
//
#include <hip/hip_runtime.h>
#include <stdint.h>

// Problem constants
#define TT 64
#define BB 32
#define VV 32000
#define EE 512
#define HH 512
#define G4 2048   // 4*H
#define NBLK 64   // persistent recurrence blocks (<< 256 CUs -> co-resident)

typedef float f32x4 __attribute__((ext_vector_type(4)));
typedef short bf16x8 __attribute__((ext_vector_type(8)));

__device__ __forceinline__ unsigned int f2bf(float f) {
    union { float f; uint32_t u; } v; v.f = f;
    uint32_t r = v.u + 0x7fffu + ((v.u >> 16) & 1u);
    return (r >> 16);
}

// ---------------------------------------------------------------------------
// prep: gather X = emb[tok] -> bf16, init h-buffer (bf16), zero grid-barrier.
// ---------------------------------------------------------------------------
__global__ __launch_bounds__(256)
void prep_kernel(const float* __restrict__ emb, const int* __restrict__ tokens,
                 const float* __restrict__ h0,
                 unsigned short* __restrict__ Xbf, unsigned short* __restrict__ hb0,
                 unsigned int* __restrict__ syncp) {
    const int NX = TT * BB * EE / 4;   // 262,144
    const int NH = BB * HH / 4;        // 4,096
    int i = blockIdx.x * 256 + threadIdx.x;
    if (i == 0) { syncp[0] = 0u; }
    if (i < NX) {
        int rrow = i >> 7;         // row = t*32+b
        int e4 = i & 127;
        int tok = tokens[rrow];
        float4 v = ((const float4*)(emb + (size_t)tok * EE))[e4];
        uint2 o;
        o.x = f2bf(v.x) | (f2bf(v.y) << 16);
        o.y = f2bf(v.z) | (f2bf(v.w) << 16);
        *(uint2*)(Xbf + (size_t)rrow * EE + e4 * 4) = o;
        return;
    }
    i -= NX;
    if (i < NH) {
        float4 v = ((const float4*)h0)[i];
        uint2 o;
        o.x = f2bf(v.x) | (f2bf(v.y) << 16);
        o.y = f2bf(v.z) | (f2bf(v.w) << 16);
        *(uint2*)(hb0 + i * 4) = o;
    }
}

// ---------------------------------------------------------------------------
// GEMM: C[M,N](f32) = A[M,K](bf16) @ B[N,K](f32, converted in staging)^T
//       + bias1[n] (+ bias2[n]).  128x128 tile, BK=64, 4 waves (2x2 of 64x64).
// (unchanged from harness-verified kernel)
// ---------------------------------------------------------------------------
#define LDA 68   // LDS row stride in shorts (64 data + 4 pad)

__global__ __launch_bounds__(256, 2)
void gemm_bt(const unsigned short* __restrict__ A, const float* __restrict__ Bm,
             float* __restrict__ Cout, const float* __restrict__ bias1,
             const float* __restrict__ bias2, int N, int K) {
    __shared__ unsigned short lA[128 * LDA];
    __shared__ unsigned short lB[128 * LDA];
    const int tid = threadIdx.x;
    const int lane = tid & 63;
    const int w = tid >> 6;
    const int m0 = blockIdx.y * 128;
    const int n0 = blockIdx.x * 128;
    const int wm = (w & 1) * 64;
    const int wn = (w >> 1) * 64;
    f32x4 acc[4][4];
#pragma unroll
    for (int i = 0; i < 4; ++i)
#pragma unroll
        for (int j = 0; j < 4; ++j) acc[i][j] = (f32x4){0.f, 0.f, 0.f, 0.f};

    for (int k0 = 0; k0 < K; k0 += 64) {
#pragma unroll
        for (int i = 0; i < 4; ++i) {
            int c = tid + 256 * i;
            int row = c >> 3;
            int kg = c & 7;
            uint4 va = *(const uint4*)(A + (size_t)(m0 + row) * K + k0 + kg * 8);
            *(uint2*)&lA[row * LDA + kg * 8]     = make_uint2(va.x, va.y);
            *(uint2*)&lA[row * LDA + kg * 8 + 4] = make_uint2(va.z, va.w);
            const float4* bp = (const float4*)(Bm + (size_t)(n0 + row) * K + k0 + kg * 8);
            float4 b0 = bp[0], b1 = bp[1];
            uint2 p0, p1;
            p0.x = f2bf(b0.x) | (f2bf(b0.y) << 16);
            p0.y = f2bf(b0.z) | (f2bf(b0.w) << 16);
            p1.x = f2bf(b1.x) | (f2bf(b1.y) << 16);
            p1.y = f2bf(b1.z) | (f2bf(b1.w) << 16);
            *(uint2*)&lB[row * LDA + kg * 8]     = p0;
            *(uint2*)&lB[row * LDA + kg * 8 + 4] = p1;
        }
        __syncthreads();
#pragma unroll
        for (int ks = 0; ks < 2; ++ks) {
            const int kgrp = ks * 4 + (lane >> 4);
            bf16x8 af[4], bfr[4];
#pragma unroll
            for (int mi = 0; mi < 4; ++mi) {
                int row = wm + mi * 16 + (lane & 15);
                union { uint2 d[2]; bf16x8 v; } u;
                u.d[0] = *(const uint2*)&lA[row * LDA + kgrp * 8];
                u.d[1] = *(const uint2*)&lA[row * LDA + kgrp * 8 + 4];
                af[mi] = u.v;
            }
#pragma unroll
            for (int ni = 0; ni < 4; ++ni) {
                int row = wn + ni * 16 + (lane & 15);
                union { uint2 d[2]; bf16x8 v; } u;
                u.d[0] = *(const uint2*)&lB[row * LDA + kgrp * 8];
                u.d[1] = *(const uint2*)&lB[row * LDA + kgrp * 8 + 4];
                bfr[ni] = u.v;
            }
#pragma unroll
            for (int mi = 0; mi < 4; ++mi)
#pragma unroll
                for (int ni = 0; ni < 4; ++ni)
                    acc[mi][ni] = __builtin_amdgcn_mfma_f32_16x16x32_bf16(
                        af[mi], bfr[ni], acc[mi][ni], 0, 0, 0);
        }
        __syncthreads();
    }
    const int col_l = lane & 15;
    const int row_l = (lane >> 4) * 4;
#pragma unroll
    for (int ni = 0; ni < 4; ++ni) {
        int col = n0 + wn + ni * 16 + col_l;
        float bv = bias1[col];
        if (bias2) bv += bias2[col];
#pragma unroll
        for (int mi = 0; mi < 4; ++mi) {
            int rowb = m0 + wm + mi * 16 + row_l;
#pragma unroll
            for (int rr = 0; rr < 4; ++rr) {
                Cout[(size_t)(rowb + rr) * N + col] = acc[mi][ni][rr] + bv;
            }
        }
    }
}

// ---------------------------------------------------------------------------
// rec: persistent fused recurrence. 64 blocks x 256 threads, one grid barrier
// per timestep (monotone atomic counter, agent-scope release/acquire).
//
// Block owns h-cols jh in [blk*8, blk*8+8). W_hh slice (32 rows x 512, rows
// interleaved as hc*4+gate) lives in VGPRs as bf16 MFMA A-fragments for the
// whole kernel. Per step: gates = W_slice @ h^T via 16x mfma_16x16x32_bf16;
// D-layout (col=lane&15=batch, row=(lane>>4)*4+reg=hc*4+gate) puts all 4
// gates of one (b, jh) in one lane -> cell update is pure per-lane VALU.
// c and (post-mask) h for the lane's (b, jh) stay in VGPRs across steps.
// h published per step as bf16 (double-buffered global, 32 KB).
// ---------------------------------------------------------------------------
__global__ __launch_bounds__(256, 1)
void rec_kernel(const float* __restrict__ XG, const float* __restrict__ Whh,
                const int* __restrict__ tokens, const float* __restrict__ h0,
                const float* __restrict__ c0, unsigned short* __restrict__ hb0,
                unsigned short* __restrict__ hb1, unsigned short* __restrict__ Htmp,
                unsigned int* __restrict__ syncp) {
    __shared__ int ltok[TT * BB];   // 8 KB
    const int tid = threadIdx.x;
    const int l = tid & 63;
    const int w = tid >> 6;
    const int mi = w >> 1;          // gate-row quadrant (A/D rows)
    const int ni = w & 1;           // batch quadrant (B/D cols)
    const int blk = blockIdx.x;

    for (int u = tid; u < TT * BB; u += 256) ltok[u] = tokens[u];

    // lane's owned output element (from D layout)
    const int b  = ni * 16 + (l & 15);          // batch
    const int hc = mi * 4 + (l >> 4);           // local h-col 0..7
    const int jh = blk * 8 + hc;                // global h col

    // A-fragment identity: local W row r = mi*16 + (l&15), k-sub = (l>>4)*8
    const int r = mi * 16 + (l & 15);
    const int hcr = r >> 2;
    const int gr = r & 3;
    const int ksub = (l >> 4) * 8;
    const float* wrow = Whh + ((size_t)gr * HH + (size_t)blk * 8 + hcr) * HH;
    bf16x8 af[16];
#pragma unroll
    for (int kc = 0; kc < 16; ++kc) {
        float4 w0 = *(const float4*)(wrow + kc * 32 + ksub);
        float4 w1 = *(const float4*)(wrow + kc * 32 + ksub + 4);
        union { unsigned short s[8]; bf16x8 v; } u;
        u.s[0] = (unsigned short)f2bf(w0.x);
        u.s[1] = (unsigned short)f2bf(w0.y);
        u.s[2] = (unsigned short)f2bf(w0.z);
        u.s[3] = (unsigned short)f2bf(w0.w);
        u.s[4] = (unsigned short)f2bf(w1.x);
        u.s[5] = (unsigned short)f2bf(w1.y);
        u.s[6] = (unsigned short)f2bf(w1.z);
        u.s[7] = (unsigned short)f2bf(w1.w);
        af[kc] = u.v;
    }

    float hprev = h0[(size_t)b * HH + jh];   // exact f32 carry for mask path
    float cprev = c0[(size_t)b * HH + jh];
    __syncthreads();   // ltok staged

    for (int t = 0; t < TT; ++t) {
        const unsigned short* hin = (t & 1) ? hb1 : hb0;
        unsigned short* hout = (t & 1) ? hb0 : hb1;

        // precomputed input-gates (issued early; latency overlaps h loads)
        const float* xg = XG + ((size_t)t * BB + b) * G4 + jh;
        float x0 = xg[0];
        float x1 = xg[HH];
        float x2 = xg[2 * HH];
        float x3 = xg[3 * HH];

        // B-fragments: lane reads h[b'][kc*32 + ksub .. +7], b' = ni*16+(l&15)
        const unsigned short* hrow = hin + (size_t)b * HH + ksub;
        f32x4 acc = {0.f, 0.f, 0.f, 0.f};
#pragma unroll
        for (int kc = 0; kc < 16; ++kc) {
            bf16x8 bfv = *(const bf16x8*)(hrow + kc * 32);
            acc = __builtin_amdgcn_mfma_f32_16x16x32_bf16(af[kc], bfv, acc, 0, 0, 0);
        }

        float gi = acc[0] + x0;
        float gf = acc[1] + x1;
        float gg = acc[2] + x2;
        float go = acc[3] + x3;
        float ig = 1.f / (1.f + __expf(-gi));
        float fg = 1.f / (1.f + __expf(-gf));
        float gt = tanhf(gg);
        float og = 1.f / (1.f + __expf(-go));
        float c_tmp = fg * cprev + ig * gt;
        float h_tmp = og * tanhf(c_tmp);
        const bool msk = ltok[t * BB + b] != 0;   // PAD == 0
        cprev = msk ? c_tmp : cprev;
        hprev = msk ? h_tmp : hprev;

        Htmp[((size_t)t * BB + b) * HH + jh] = (unsigned short)f2bf(h_tmp);
        hout[(size_t)b * HH + jh] = (unsigned short)f2bf(hprev);

        if (t < TT - 1) {
            // grid barrier: all blocks' h published before anyone reads it
            __syncthreads();
            if (tid == 0) {
                __hip_atomic_fetch_add(syncp, 1u, __ATOMIC_RELEASE,
                                       __HIP_MEMORY_SCOPE_AGENT);
                const unsigned int tgt = (unsigned int)(t + 1) * NBLK;
                while (__hip_atomic_load(syncp, __ATOMIC_RELAXED,
                                         __HIP_MEMORY_SCOPE_AGENT) < tgt) {
                    __builtin_amdgcn_s_sleep(2);
                }
                (void)__hip_atomic_load(syncp, __ATOMIC_ACQUIRE,
                                        __HIP_MEMORY_SCOPE_AGENT);
            }
            __syncthreads();
        }
    }
}

// ---------------------------------------------------------------------------
extern "C" void kernel_launch(void* const* d_in, const int* in_sizes, int n_in,
                              void* d_out, int out_size, void* d_ws, size_t ws_size,
                              hipStream_t stream) {
    const int*   tokens = (const int*)d_in[0];
    const float* emb    = (const float*)d_in[1];
    const float* W_ih   = (const float*)d_in[2];
    const float* W_hh   = (const float*)d_in[3];
    const float* b_ih   = (const float*)d_in[4];
    const float* b_hh   = (const float*)d_in[5];
    const float* W_fc   = (const float*)d_in[6];
    const float* b_fc   = (const float*)d_in[7];
    const float* h0     = (const float*)d_in[8];
    const float* c0     = (const float*)d_in[9];

    char* ws = (char*)d_ws;
    size_t o = 0;
    unsigned short* Xbf  = (unsigned short*)(ws + o); o += (size_t)TT * BB * EE * 2;  //  2.10 MB
    unsigned short* Htmp = (unsigned short*)(ws + o); o += (size_t)TT * BB * HH * 2;  //  2.10 MB
    float* XG = (float*)(ws + o); o += (size_t)TT * BB * G4 * 4;                      // 16.78 MB
    unsigned short* hb0 = (unsigned short*)(ws + o); o += (size_t)BB * HH * 2;        // 32 KB
    unsigned short* hb1 = (unsigned short*)(ws + o); o += (size_t)BB * HH * 2;        // 32 KB
    unsigned int* syncp = (unsigned int*)(ws + o); o += 64;
    (void)ws_size; (void)in_sizes; (void)n_in; (void)out_size;

    // 1) gather X -> bf16, h0 -> bf16 h-buffer, zero barrier counter
    prep_kernel<<<1040, 256, 0, stream>>>(emb, tokens, h0, Xbf, hb0, syncp);
    // 2) XG = X @ W_ih^T + b_ih + b_hh   (M=2048, N=2048, K=512, f32 out)
    dim3 gx(G4 / 128, (TT * BB) / 128);
    gemm_bt<<<gx, 256, 0, stream>>>(Xbf, W_ih, XG, b_ih, b_hh, G4, EE);
    // 3) recurrence: ONE persistent kernel, 64 steps, grid barrier per step
    rec_kernel<<<NBLK, 256, 0, stream>>>(XG, W_hh, tokens, h0, c0, hb0, hb1,
                                         Htmp, syncp);
    // 4) logits = Htmp @ W_fc^T + b_fc   (M=2048, N=32000, K=512, f32 out)
    dim3 gp(VV / 128, (TT * BB) / 128);
    gemm_bt<<<gp, 256, 0, stream>>>(Htmp, W_fc, (float*)d_out, b_fc, nullptr, VV, HH);
}

// Round 4
// 875.502 us; speedup vs baseline: 1.0826x; 1.0826x over previous
//
#include <hip/hip_runtime.h>
#include <stdint.h>

// Problem constants
#define TT 64
#define BB 32
#define VV 32000
#define EE 512
#define HH 512
#define G4 2048   // 4*H
#define NBLK 64   // persistent recurrence blocks (<< 256 CUs -> co-resident)

typedef float f32x4 __attribute__((ext_vector_type(4)));
typedef short bf16x8 __attribute__((ext_vector_type(8)));

__device__ __forceinline__ unsigned int f2bf(float f) {
    union { float f; uint32_t u; } v; v.f = f;
    uint32_t r = v.u + 0x7fffu + ((v.u >> 16) & 1u);
    return (r >> 16);
}
__device__ __forceinline__ uint2 pack4(float4 v) {
    uint2 o;
    o.x = f2bf(v.x) | (f2bf(v.y) << 16);
    o.y = f2bf(v.z) | (f2bf(v.w) << 16);
    return o;
}

// async global->LDS, 16B per lane. LDS dest is wave-uniform base + lane*16;
// our chunk layout is lane-linear so per-lane pointers are consistent.
__device__ __forceinline__ void gload16(const unsigned short* g, unsigned short* l) {
    __builtin_amdgcn_global_load_lds(
        (const __attribute__((address_space(1))) unsigned int*)g,
        (__attribute__((address_space(3))) unsigned int*)l, 16, 0, 0);
}

// ---------------------------------------------------------------------------
// prep (grid-stride): gather X=emb[tok]->bf16, h0->bf16, W_ih->bf16,
// W_fc->bf16, zero sync region.
// ---------------------------------------------------------------------------
__global__ __launch_bounds__(256)
void prep_kernel(const float* __restrict__ emb, const int* __restrict__ tokens,
                 const float* __restrict__ h0, const float* __restrict__ Wih,
                 const float* __restrict__ Wfc,
                 unsigned short* __restrict__ Xbf, unsigned short* __restrict__ hb0,
                 unsigned short* __restrict__ Wib, unsigned short* __restrict__ Wfb,
                 unsigned int* __restrict__ syncp) {
    const int NX = TT * BB * EE / 4;    // 262,144 float4 chunks
    const int NH = BB * HH / 4;         // 4,096
    const int NWI = G4 * EE / 4;        // 262,144
    const int NWF = VV * HH / 4;        // 4,096,000
    const int NS = NBLK * 16 + 16;      // 1,040 sync words
    const long total = (long)NX + NH + NWI + NWF + NS;
    for (long idx = (long)blockIdx.x * 256 + threadIdx.x; idx < total;
         idx += (long)gridDim.x * 256) {
        long i = idx;
        if (i < NX) {
            int rrow = (int)(i >> 7);        // row = t*32+b
            int e4 = (int)(i & 127);
            int tok = tokens[rrow];
            float4 v = ((const float4*)(emb + (size_t)tok * EE))[e4];
            *(uint2*)(Xbf + (size_t)rrow * EE + e4 * 4) = pack4(v);
            continue;
        }
        i -= NX;
        if (i < NH) {
            float4 v = ((const float4*)h0)[i];
            *(uint2*)(hb0 + i * 4) = pack4(v);
            continue;
        }
        i -= NH;
        if (i < NWI) {
            float4 v = ((const float4*)Wih)[i];
            *(uint2*)(Wib + i * 4) = pack4(v);
            continue;
        }
        i -= NWI;
        if (i < NWF) {
            float4 v = ((const float4*)Wfc)[i];
            *(uint2*)(Wfb + i * 4) = pack4(v);
            continue;
        }
        i -= NWF;
        syncp[i] = 0u;
    }
}

// ---------------------------------------------------------------------------
// GEMM (m97 structure): C[M,N](f32) = A[M,K](bf16) @ B[N,K](bf16)^T + bias.
// 128x128 tile, BK=64, 4 waves (2x2 of 64x64), global_load_lds width-16
// staging into linear LDS, bijective XCD swizzle (nwg % 8 == 0).
// mode==1: write C in XG4 layout [row][n&511][n>>9] (f32) for rec_kernel.
// ---------------------------------------------------------------------------
__global__ __launch_bounds__(256, 2)
void gemm_bb(const unsigned short* __restrict__ A, const unsigned short* __restrict__ B,
             float* __restrict__ Cout, const float* __restrict__ bias1,
             const float* __restrict__ bias2, int N, int K, int ntn, int mode) {
    __shared__ unsigned short lA[128 * 64];
    __shared__ unsigned short lB[128 * 64];
    const int tid = threadIdx.x;
    const int lane = tid & 63;
    const int w = tid >> 6;
    // XCD-aware swizzle (requires gridDim.x % 8 == 0; true for 256 and 4000)
    const int nwg = gridDim.x;
    const int cpx = nwg >> 3;
    const int wid = (blockIdx.x & 7) * cpx + (blockIdx.x >> 3);
    const int m0 = (wid / ntn) * 128;
    const int n0 = (wid % ntn) * 128;
    const int wm = (w & 1) * 64;
    const int wn = (w >> 1) * 64;
    f32x4 acc[4][4];
#pragma unroll
    for (int i = 0; i < 4; ++i)
#pragma unroll
        for (int j = 0; j < 4; ++j) acc[i][j] = (f32x4){0.f, 0.f, 0.f, 0.f};

    for (int k0 = 0; k0 < K; k0 += 64) {
#pragma unroll
        for (int i = 0; i < 4; ++i) {
            int c = i * 256 + tid;       // 1024 chunks of 16B per operand
            int row = c >> 3;
            int kg = c & 7;
            gload16(A + (size_t)(m0 + row) * K + k0 + kg * 8, &lA[c * 8]);
            gload16(B + (size_t)(n0 + row) * K + k0 + kg * 8, &lB[c * 8]);
        }
        __syncthreads();
#pragma unroll
        for (int ks = 0; ks < 2; ++ks) {
            const int kgrp = ks * 4 + (lane >> 4);
            bf16x8 af[4], bfr[4];
#pragma unroll
            for (int mi = 0; mi < 4; ++mi) {
                int row = wm + mi * 16 + (lane & 15);
                af[mi] = *(const bf16x8*)&lA[row * 64 + kgrp * 8];
            }
#pragma unroll
            for (int ni = 0; ni < 4; ++ni) {
                int row = wn + ni * 16 + (lane & 15);
                bfr[ni] = *(const bf16x8*)&lB[row * 64 + kgrp * 8];
            }
#pragma unroll
            for (int mi = 0; mi < 4; ++mi)
#pragma unroll
                for (int ni = 0; ni < 4; ++ni)
                    acc[mi][ni] = __builtin_amdgcn_mfma_f32_16x16x32_bf16(
                        af[mi], bfr[ni], acc[mi][ni], 0, 0, 0);
        }
        __syncthreads();
    }
    // epilogue: D layout col=lane&15 (n), row=(lane>>4)*4+reg (m)
    const int col_l = lane & 15;
    const int row_l = (lane >> 4) * 4;
#pragma unroll
    for (int ni = 0; ni < 4; ++ni) {
        int col = n0 + wn + ni * 16 + col_l;
        float bv = bias1[col];
        if (bias2) bv += bias2[col];
#pragma unroll
        for (int mi = 0; mi < 4; ++mi) {
            int rowb = m0 + wm + mi * 16 + row_l;
#pragma unroll
            for (int rr = 0; rr < 4; ++rr) {
                size_t idx;
                if (mode) {
                    idx = (size_t)(rowb + rr) * N + ((col & 511) << 2) + (col >> 9);
                } else {
                    idx = (size_t)(rowb + rr) * N + col;
                }
                Cout[idx] = acc[mi][ni][rr] + bv;
            }
        }
    }
}

// ---------------------------------------------------------------------------
// rec: persistent fused recurrence. 64 blocks x 256 threads.
// Per step: gates = W_slice @ h^T via 16x mfma_16x16x32_bf16 (W in VGPRs all
// kernel); D-layout puts all 4 gates of one (b, jh) in one lane's acc regs.
// XG read as ONE float4/lane (XG4 layout), prefetched for t+1 BEFORE the
// barrier (immutable -> survives L2 invalidate in registers).
// Barrier: flag-tree. Block i>0 release-stores flags[i] (own 64B line);
// block 0 polls flags[1..63] lane-parallel (its own arrival is implied),
// acquire-fences, then release-stores `go`; others spin on `go` + acquire.
// ---------------------------------------------------------------------------
__global__ __launch_bounds__(256, 1)
void rec_kernel(const float* __restrict__ XG4, const float* __restrict__ Whh,
                const int* __restrict__ tokens, const float* __restrict__ h0,
                const float* __restrict__ c0, unsigned short* __restrict__ hb0,
                unsigned short* __restrict__ hb1, unsigned short* __restrict__ Htmp,
                unsigned int* __restrict__ syncp) {
    __shared__ int ltok[TT * BB];   // 8 KB
    const int tid = threadIdx.x;
    const int l = tid & 63;
    const int w = tid >> 6;
    const int mi = w >> 1;          // gate-row quadrant (A/D rows)
    const int ni = w & 1;           // batch quadrant (B/D cols)
    const int blk = blockIdx.x;
    unsigned int* flags = syncp;              // flags[blk*16], 64B-strided
    unsigned int* go = syncp + NBLK * 16;     // separate line

    for (int u = tid; u < TT * BB; u += 256) ltok[u] = tokens[u];

    // lane's owned output element (from D layout)
    const int b  = ni * 16 + (l & 15);          // batch
    const int hc = mi * 4 + (l >> 4);           // local h-col 0..7
    const int jh = blk * 8 + hc;                // global h col

    // A-fragment identity: local W row r = mi*16 + (l&15), k-sub = (l>>4)*8
    const int r = mi * 16 + (l & 15);
    const int hcr = r >> 2;
    const int gr = r & 3;
    const int ksub = (l >> 4) * 8;
    const float* wrow = Whh + ((size_t)gr * HH + (size_t)blk * 8 + hcr) * HH;
    bf16x8 af[16];
#pragma unroll
    for (int kc = 0; kc < 16; ++kc) {
        float4 w0 = *(const float4*)(wrow + kc * 32 + ksub);
        float4 w1 = *(const float4*)(wrow + kc * 32 + ksub + 4);
        union { unsigned short s[8]; bf16x8 v; } u;
        u.s[0] = (unsigned short)f2bf(w0.x);
        u.s[1] = (unsigned short)f2bf(w0.y);
        u.s[2] = (unsigned short)f2bf(w0.z);
        u.s[3] = (unsigned short)f2bf(w0.w);
        u.s[4] = (unsigned short)f2bf(w1.x);
        u.s[5] = (unsigned short)f2bf(w1.y);
        u.s[6] = (unsigned short)f2bf(w1.z);
        u.s[7] = (unsigned short)f2bf(w1.w);
        af[kc] = u.v;
    }

    float hprev = h0[(size_t)b * HH + jh];   // exact f32 carry for mask path
    float cprev = c0[(size_t)b * HH + jh];

    // XG4: one float4 per lane per step; 4 lanes sharing b cover one 64B line
    const float* xgp = XG4 + (size_t)b * G4 + (size_t)jh * 4;
    float4 xv = *(const float4*)xgp;   // t = 0
    __syncthreads();   // ltok staged

    for (int t = 0; t < TT; ++t) {
        const unsigned short* hin = (t & 1) ? hb1 : hb0;
        unsigned short* hout = (t & 1) ? hb0 : hb1;

        // B-fragments: lane reads h[b][kc*32 + ksub .. +7]
        const unsigned short* hrow = hin + (size_t)b * HH + ksub;
        f32x4 acc = {0.f, 0.f, 0.f, 0.f};
#pragma unroll
        for (int kc = 0; kc < 16; ++kc) {
            bf16x8 bfv = *(const bf16x8*)(hrow + kc * 32);
            acc = __builtin_amdgcn_mfma_f32_16x16x32_bf16(af[kc], bfv, acc, 0, 0, 0);
        }

        float gi = acc[0] + xv.x;
        float gf = acc[1] + xv.y;
        float gg = acc[2] + xv.z;
        float go_ = acc[3] + xv.w;
        float ig = 1.f / (1.f + __expf(-gi));
        float fg = 1.f / (1.f + __expf(-gf));
        float gt = tanhf(gg);
        float og = 1.f / (1.f + __expf(-go_));
        float c_tmp = fg * cprev + ig * gt;
        float h_tmp = og * tanhf(c_tmp);
        const bool msk = ltok[t * BB + b] != 0;   // PAD == 0
        cprev = msk ? c_tmp : cprev;
        hprev = msk ? h_tmp : hprev;

        Htmp[((size_t)t * BB + b) * HH + jh] = (unsigned short)f2bf(h_tmp);
        hout[(size_t)b * HH + jh] = (unsigned short)f2bf(hprev);

        if (t < TT - 1) {
            // prefetch next step's XG into registers BEFORE the barrier
            float4 xn = *(const float4*)(xgp + (size_t)(t + 1) * BB * G4);
            __syncthreads();   // all waves' h stores issued
            if (blk == 0) {
                // poll other blocks' flags (own arrival implied); tid 1..63
                if (tid > 0 && tid < NBLK) {
                    while (__hip_atomic_load(&flags[tid * 16], __ATOMIC_RELAXED,
                                             __HIP_MEMORY_SCOPE_AGENT) <= (unsigned)t)
                        __builtin_amdgcn_s_sleep(1);
                }
                __syncthreads();   // poll complete
                if (tid == 0) {
                    // acquire: pair with blocks' flag release-stores so the
                    // following go release carries their h-writes; also
                    // freshens our own view for the upcoming h reads.
                    __builtin_amdgcn_fence(__ATOMIC_ACQUIRE, "agent");
                    __hip_atomic_store(go, (unsigned)(t + 1), __ATOMIC_RELEASE,
                                       __HIP_MEMORY_SCOPE_AGENT);
                }
            } else {
                if (tid == 0) {
                    __hip_atomic_store(&flags[blk * 16], (unsigned)(t + 1),
                                       __ATOMIC_RELEASE, __HIP_MEMORY_SCOPE_AGENT);
                    while (__hip_atomic_load(go, __ATOMIC_RELAXED,
                                             __HIP_MEMORY_SCOPE_AGENT) <= (unsigned)t)
                        __builtin_amdgcn_s_sleep(1);
                    __builtin_amdgcn_fence(__ATOMIC_ACQUIRE, "agent");
                }
            }
            __syncthreads();
            xv = xn;
        }
    }
}

// ---------------------------------------------------------------------------
extern "C" void kernel_launch(void* const* d_in, const int* in_sizes, int n_in,
                              void* d_out, int out_size, void* d_ws, size_t ws_size,
                              hipStream_t stream) {
    const int*   tokens = (const int*)d_in[0];
    const float* emb    = (const float*)d_in[1];
    const float* W_ih   = (const float*)d_in[2];
    const float* W_hh   = (const float*)d_in[3];
    const float* b_ih   = (const float*)d_in[4];
    const float* b_hh   = (const float*)d_in[5];
    const float* W_fc   = (const float*)d_in[6];
    const float* b_fc   = (const float*)d_in[7];
    const float* h0     = (const float*)d_in[8];
    const float* c0     = (const float*)d_in[9];

    char* ws = (char*)d_ws;
    size_t o = 0;
    unsigned short* Xbf  = (unsigned short*)(ws + o); o += (size_t)TT * BB * EE * 2;  //  2.10 MB
    unsigned short* Htmp = (unsigned short*)(ws + o); o += (size_t)TT * BB * HH * 2;  //  2.10 MB
    float* XG = (float*)(ws + o); o += (size_t)TT * BB * G4 * 4;                      // 16.78 MB
    unsigned short* Wib = (unsigned short*)(ws + o); o += (size_t)G4 * EE * 2;        //  2.10 MB
    unsigned short* Wfb = (unsigned short*)(ws + o); o += (size_t)VV * HH * 2;        // 32.77 MB
    unsigned short* hb0 = (unsigned short*)(ws + o); o += (size_t)BB * HH * 2;        // 32 KB
    unsigned short* hb1 = (unsigned short*)(ws + o); o += (size_t)BB * HH * 2;        // 32 KB
    unsigned int* syncp = (unsigned int*)(ws + o); o += (NBLK * 16 + 16) * 4;
    (void)ws_size; (void)in_sizes; (void)n_in; (void)out_size;

    // 1) gather X->bf16, h0->bf16, W_ih/W_fc->bf16, zero sync region
    prep_kernel<<<2048, 256, 0, stream>>>(emb, tokens, h0, W_ih, W_fc,
                                          Xbf, hb0, Wib, Wfb, syncp);
    // 2) XG4 = X @ W_ih^T + b_ih + b_hh  (M=2048, N=2048, K=512; XG4 layout)
    gemm_bb<<<(G4 / 128) * ((TT * BB) / 128), 256, 0, stream>>>(
        Xbf, Wib, XG, b_ih, b_hh, G4, EE, G4 / 128, 1);
    // 3) recurrence: ONE persistent kernel, 64 steps, flag-tree barrier
    rec_kernel<<<NBLK, 256, 0, stream>>>(XG, W_hh, tokens, h0, c0, hb0, hb1,
                                         Htmp, syncp);
    // 4) logits = Htmp @ W_fc^T + b_fc  (M=2048, N=32000, K=512, f32 out)
    gemm_bb<<<(VV / 128) * ((TT * BB) / 128), 256, 0, stream>>>(
        Htmp, Wfb, (float*)d_out, b_fc, nullptr, VV, HH, VV / 128, 0);
}